// Round 23
// baseline (204.972 us; speedup 1.0000x reference)
//
#include <hip/hip_runtime.h>
#include <math.h>
#include <string.h>

#define NB 8
#define NS 1024
#define NE 1024
#define NH 16
#define ND 64
#define NL 1024

typedef __attribute__((ext_vector_type(8))) short short8;
typedef __attribute__((ext_vector_type(4))) float f32x4;
typedef __attribute__((ext_vector_type(16))) float f32x16;

// native HW bf16 conversion (v_cvt on gfx950, RNE)
__device__ __forceinline__ ushort f2bf(float f) {
    union { __bf16 h; ushort u; } v;
    v.h = (__bf16)f;
    return v.u;
}
__device__ __forceinline__ float bf2f(ushort u) {
    union { unsigned u; float f; } v; v.u = ((unsigned)u) << 16;
    return v.f;
}

__device__ __forceinline__ void stage16(const ushort* gsrc, ushort* lbase) {
    __builtin_amdgcn_global_load_lds((const __attribute__((address_space(1))) void*)gsrc,
                                     (__attribute__((address_space(3))) void*)lbase,
                                     16, 0, 0);
}

// ---------------- merged cast kernel ----------------
// blocks [0,8192): x float4 -> bf16x4
// blocks [8192,12288): W4 float4 -> bf16x4 (Wq|Wk|Wv|Wo)
// blocks [12288,...): PEK + PEV fragment-major scalars
__global__ __launch_bounds__(256)
void cast_all(const float* __restrict__ x,
              const float* __restrict__ Wq, const float* __restrict__ Wk,
              const float* __restrict__ Wv, const float* __restrict__ Wo,
              const float* __restrict__ pek, const float* __restrict__ pev,
              ushort* __restrict__ xb, ushort* __restrict__ Wqb,
              ushort* __restrict__ outK, ushort* __restrict__ outV) {
    const int blk = blockIdx.x;
    if (blk < 8192) {
        int i = blk * 256 + threadIdx.x;
        float4 v = ((const float4*)x)[i];
        ((ushort4*)xb)[i] = make_ushort4(f2bf(v.x), f2bf(v.y), f2bf(v.z), f2bf(v.w));
    } else if (blk < 12288) {
        int i = (blk - 8192) * 256 + threadIdx.x;   // [0, 4*262144)
        const int seg = i >> 18, j = i & 262143;
        const float* src = seg == 0 ? Wq : seg == 1 ? Wk : seg == 2 ? Wv : Wo;
        float4 v = ((const float4*)src)[j];
        ((ushort4*)Wqb)[i] = make_ushort4(f2bf(v.x), f2bf(v.y), f2bf(v.z), f2bf(v.w));
    } else {
        int i = (blk - 12288) * 256 + threadIdx.x;
        if (i < 2049 * 64) {
            const int r = i >> 6, d = i & 63;
            outK[(size_t)(d >> 4) * 32784 + (size_t)r * 16 + (d & 15)] = f2bf(pek[i]);
        } else {
            int ii = i - 2049 * 64;
            if (ii >= 64 * 1056) return;
            const int d = ii / 1056, r = ii % 1056;
            const int m = r >> 5, cc = (r >> 4) & 1, hi = (r >> 3) & 1, j = r & 7;
            const int a = d >> 5, sl = d & 31;
            outV[(size_t)m * 2048 + cc * 1024 + a * 512 + (sl * 2 + hi) * 8 + j] =
                f2bf(pev[(size_t)(r + 1) * ND + d]);
        }
    }
}

// ---------------- MFMA GEMM: C = A @ W^T (bf16 in, fp32 acc) ----------------
// MODE 1: fp32 row-major [M,1024]                         (out-proj)
// MODE 5: merged QKV epilogue, N=3072; block-uniform seg = n0>>10:
//   seg 0 -> Q bf16 row-major [B,H,S,D]
//   seg 1 -> K fragment-major
//   seg 2 -> V fragment-major
template<int MODE>
__global__ __launch_bounds__(256)
void gemm_mfma(const ushort* __restrict__ A, const ushort* __restrict__ W,
               float* __restrict__ Cf, ushort* __restrict__ Cb)
{
    constexpr int K = 1024;
    __shared__ __align__(16) ushort As[128 * 32];
    __shared__ __align__(16) ushort Bs[128 * 32];
    const int tid = threadIdx.x;
    const int w   = tid >> 6;
    const int l   = tid & 63;
    const int m0  = blockIdx.x * 128;
    const int n0  = blockIdx.y * 128;
    const int wr  = w >> 1, wc = w & 1;

    const int srow = 16 * w + (l >> 2);
    const int scol = (l & 3) * 8;
    const ushort* aptr = A + (size_t)(m0 + srow) * K + scol;
    const ushort* bptr = W + (size_t)(n0 + srow) * K + scol;
    ushort* asl = &As[w * 512];
    ushort* bsl = &Bs[w * 512];

    const int fl = l & 15, fk = (l >> 4) * 8;

    f32x4 acc[4][4] = {};

    for (int k0 = 0; k0 < K; k0 += 32) {
        __syncthreads();
        stage16(aptr + k0,                    asl);
        stage16(aptr + k0 + (size_t)64 * K,   asl + 2048);
        stage16(bptr + k0,                    bsl);
        stage16(bptr + k0 + (size_t)64 * K,   bsl + 2048);
        __syncthreads();

        short8 af[4], bf[4];
        #pragma unroll
        for (int i = 0; i < 4; ++i)
            af[i] = *(const short8*)&As[(wr * 64 + i * 16 + fl) * 32 + fk];
        #pragma unroll
        for (int j = 0; j < 4; ++j)
            bf[j] = *(const short8*)&Bs[(wc * 64 + j * 16 + fl) * 32 + fk];
        #pragma unroll
        for (int i = 0; i < 4; ++i)
            #pragma unroll
            for (int j = 0; j < 4; ++j)
                acc[i][j] = __builtin_amdgcn_mfma_f32_16x16x32_bf16(af[i], bf[j], acc[i][j], 0, 0, 0);
    }

    #pragma unroll
    for (int i = 0; i < 4; ++i) {
        #pragma unroll
        for (int j = 0; j < 4; ++j) {
            #pragma unroll
            for (int q = 0; q < 4; ++q) {
                const int m = m0 + wr * 64 + i * 16 + (l >> 4) * 4 + q;
                const int n = n0 + wc * 64 + j * 16 + fl;
                const float vv = acc[i][j][q];
                if (MODE == 5) {
                    const int seg = n0 >> 10;        // block-uniform
                    const int nn  = n & 1023;
                    const int b = m >> 10, s = m & 1023;
                    const int h = nn >> 6, d = nn & 63;
                    const int bh = b * NH + h;
                    if (seg == 0) {
                        Cb[(((size_t)bh) * NS + s) * ND + d] = f2bf(vv);
                    } else if (seg == 1) {
                        (Cb + (size_t)8388608)
                            [((size_t)bh * 4 + (d >> 4)) * 16384 + (size_t)s * 16 + (d & 15)] = f2bf(vv);
                    } else {
                        const int it = s >> 5, trel = s & 31;
                        const int c = trel >> 4, hi2 = (trel >> 3) & 1, jj = trel & 7;
                        const int a = d >> 5, sl2 = d & 31;
                        (Cb + (size_t)16777216)
                            [(size_t)bh * 65536 + it * 2048 +
                             ((a * 2 + c) * 64 + sl2 * 2 + hi2) * 8 + jj] = f2bf(vv);
                    }
                } else {
                    Cf[(size_t)m * NE + n] = vv;
                }
            }
        }
    }
}

// ---------------- MFMA fused attention with RPE ----------------
// Single-buffered Mpt (12.8 KB LDS -> 12 blocks/CU = 3 waves/SIMD).
// Round-21's WAR-ordering hazard fixed: packed M writes go through
// __builtin_memcpy (char-typed, aliases the ushort reads -> the compiler
// cannot hoist window-k+1 ds_writes above window-k ds_reads).
__global__ __launch_bounds__(64, 2)
void attn_mfma(const ushort* __restrict__ Qb, const ushort* __restrict__ Kf_,
               const ushort* __restrict__ Vf_, const ushort* __restrict__ PEKf,
               const ushort* __restrict__ PEVf, ushort* __restrict__ AO)
{
    const int idx = blockIdx.x;
    const int st  = 31 - (idx >> 7);     // longest blocks first
    const int bh  = idx & 127;
    const int b   = bh >> 4, h = bh & 15;
    const int n2  = h * NB + b;          // torch view(S,H,B,S).transpose(0,2) shuffle
    const int b2  = n2 >> 4, h2 = n2 & 15;
    const int s0  = st * 32;

    const int lane = threadIdx.x;
    const int sl   = lane & 31;
    const int hi   = lane >> 5;

    const int T      = st + 1;
    const int Ppairs = (T - 1) >> 1;     // unmasked pairs
    const int i0     = 2 * Ppairs;       // first trailing tile (1 or 2 trail)

    __shared__ __align__(16) ushort Mpt[96][34];   // [u][s], stride 34 (68B) — 6528 B
    __shared__ __align__(16) ushort Pb2[32][98];   // 6272 B

    for (int t = lane; t < 32 * 98 / 2; t += 64) ((int*)Pb2)[t] = 0;

    const ushort* qptr  = Qb + (((size_t)bh * NS) + s0 + sl) * ND + hi * 8;
    const ushort* q2ptr = Qb + ((((size_t)b2 * NH + h2) * NS) + s0 + sl) * ND + hi * 8;
    short8 qf[4], q2f[4];
    #pragma unroll
    for (int c = 0; c < 4; ++c) {
        qf[c]  = *(const short8*)(qptr  + 16 * c);
        q2f[c] = *(const short8*)(q2ptr + 16 * c);
    }

    const ushort* kfb  = Kf_ + (size_t)bh * 65536 + sl * 16 + hi * 8;
    const ushort* vfb  = Vf_ + (size_t)bh * 65536 + (sl * 2 + hi) * 8;
    const ushort* efb  = PEKf + sl * 16 + hi * 8;
    const ushort* pevw = PEVf + (size_t)(31 - st) * 2048 + (sl * 2 + hi) * 8;
    const int RBASE = NL - 31 - s0;

    // chunk c -> Mpt[cb+sl][*]; packed b32 writes via memcpy (alias-safe)
    auto mpchunk = [&](int c, int cb) {
        f32x16 cm = {};
        #pragma unroll
        for (int c4 = 0; c4 < 4; ++c4) {
            short8 ef = *(const short8*)(efb + (size_t)c4 * 32784 +
                                         (size_t)(RBASE + 32 * c) * 16);
            cm = __builtin_amdgcn_mfma_f32_32x32x16_bf16(q2f[c4], ef, cm, 0, 0, 0);
        }
        #pragma unroll
        for (int w2 = 0; w2 < 8; ++w2) {
            const int q = 2 * w2;
            const int srow = (q & 3) + 8 * (q >> 2) + 4 * hi;   // even
            unsigned pk = (unsigned)f2bf(cm[q]) | ((unsigned)f2bf(cm[q + 1]) << 16);
            __builtin_memcpy(&Mpt[cb + sl][srow], &pk, 4);
        }
    };

    f32x16 acc0 = {}, acc1 = {};
    float mrow = -1e30f, lrow = 0.f;
    short8 eaA[2][2];

    __builtin_amdgcn_s_setprio(1);
    mpchunk(0, 0);
    mpchunk(1, 32);
    mpchunk(2, 64);
    __builtin_amdgcn_s_setprio(0);
    #pragma unroll
    for (int cc = 0; cc < 2; ++cc)
        #pragma unroll
        for (int a = 0; a < 2; ++a)
            eaA[cc][a] = *(const short8*)(pevw + cc * 1024 + a * 512);

    // ================= pair loop =================
    for (int k = 0; k < Ppairs; ++k) {
        const int t0 = 64 * k;

        short8 kfA[4], kfB[4], vaA[2][2];
        #pragma unroll
        for (int c = 0; c < 4; ++c) {
            kfA[c] = *(const short8*)(kfb + c * 16384 + (size_t)t0 * 16);
            kfB[c] = *(const short8*)(kfb + c * 16384 + (size_t)(t0 + 32) * 16);
        }
        #pragma unroll
        for (int c = 0; c < 2; ++c)
            #pragma unroll
            for (int a = 0; a < 2; ++a)
                vaA[c][a] = *(const short8*)(vfb + (size_t)(2 * k) * 2048 + (a * 2 + c) * 512);

        f32x16 csw0 = {}, csw1 = {};
        __builtin_amdgcn_s_setprio(1);
        #pragma unroll
        for (int c = 0; c < 4; ++c)
            csw0 = __builtin_amdgcn_mfma_f32_32x32x16_bf16(kfA[c], qf[c], csw0, 0, 0, 0);
        #pragma unroll
        for (int c = 0; c < 4; ++c)
            csw1 = __builtin_amdgcn_mfma_f32_32x32x16_bf16(kfB[c], qf[c], csw1, 0, 0, 0);
        __builtin_amdgcn_s_setprio(0);

        float sc[32];
        #pragma unroll
        for (int q = 0; q < 16; ++q) {
            const int trow = (q & 3) + 8 * (q >> 2) + 4 * hi;
            const int u = trow + 31 - sl;
            sc[q]      = (csw0[q] + bf2f(Mpt[u][sl]))      * 0.125f;
            sc[16 + q] = (csw1[q] + bf2f(Mpt[u + 32][sl])) * 0.125f;
        }

        float tm16[16], tm8[8], tm4[4];
        #pragma unroll
        for (int q = 0; q < 16; ++q) tm16[q] = fmaxf(sc[q], sc[q + 16]);
        #pragma unroll
        for (int q = 0; q < 8; ++q) tm8[q] = fmaxf(tm16[q], tm16[q + 8]);
        #pragma unroll
        for (int q = 0; q < 4; ++q) tm4[q] = fmaxf(tm8[q], tm8[q + 4]);
        float tmax = fmaxf(fmaxf(tm4[0], tm4[1]), fmaxf(tm4[2], tm4[3]));
        tmax = fmaxf(tmax, __shfl_xor(tmax, 32));
        if (!__all(tmax <= mrow + 8.f)) {
            const float mnew = fmaxf(mrow, tmax);
            const float r = __expf(mrow - mnew);
            lrow *= r;
            acc0 *= r; acc1 *= r;
            mrow = mnew;
        }
        float ps[32];
        #pragma unroll
        for (int q = 0; q < 32; ++q) ps[q] = __expf(sc[q] - mrow);
        float ls16[16], ls8[8], ls4[4];
        #pragma unroll
        for (int q = 0; q < 16; ++q) ls16[q] = ps[q] + ps[q + 16];
        #pragma unroll
        for (int q = 0; q < 8; ++q) ls8[q] = ls16[q] + ls16[q + 8];
        #pragma unroll
        for (int q = 0; q < 4; ++q) ls4[q] = ls8[q] + ls8[q + 4];
        float lsum = (ls4[0] + ls4[1]) + (ls4[2] + ls4[3]);
        lsum += __shfl_xor(lsum, 32);
        lrow += lsum;

        #pragma unroll
        for (int q = 0; q < 16; ++q) {
            const int trow = (q & 3) + 8 * (q >> 2) + 4 * hi;
            Pb2[sl][trow + 31 - sl] = f2bf(ps[q]);
            Pb2[sl][trow + 63 - sl] = f2bf(ps[16 + q]);
        }

        // window k+1 chunks overwrite the single buffer AFTER this window's
        // gather reads (memcpy writes alias-order vs the ushort reads)
        __builtin_amdgcn_s_setprio(1);
        mpchunk(2 * k + 2, 0);
        mpchunk(2 * k + 3, 32);
        mpchunk(2 * k + 4, 64);
        __builtin_amdgcn_s_setprio(0);

        short8 eaB[2][2], eaC[2][2];
        #pragma unroll
        for (int cc = 0; cc < 2; ++cc)
            #pragma unroll
            for (int a = 0; a < 2; ++a) {
                eaB[cc][a] = *(const short8*)(pevw + (size_t)(2 * k + 1) * 2048 + cc * 1024 + a * 512);
                eaC[cc][a] = *(const short8*)(pevw + (size_t)(2 * k + 2) * 2048 + cc * 1024 + a * 512);
            }

        __builtin_amdgcn_s_setprio(1);
        #pragma unroll
        for (int c = 0; c < 2; ++c) {
            float shc[8];
            #pragma unroll
            for (int j = 0; j < 8; ++j) shc[j] = __shfl_xor(ps[8 * c + j], 32);
            short8 bfrag;
            #pragma unroll
            for (int j = 0; j < 8; ++j) {
                float pv;
                if (j < 4) pv = hi ? shc[4 + j]    : ps[8 * c + j];
                else       pv = hi ? ps[8 * c + j] : shc[j - 4];
                bfrag[j] = (short)f2bf(pv);
            }
            acc0 = __builtin_amdgcn_mfma_f32_32x32x16_bf16(vaA[c][0], bfrag, acc0, 0, 0, 0);
            acc1 = __builtin_amdgcn_mfma_f32_32x32x16_bf16(vaA[c][1], bfrag, acc1, 0, 0, 0);
        }
        short8 vaB[2][2];
        #pragma unroll
        for (int c = 0; c < 2; ++c)
            #pragma unroll
            for (int a = 0; a < 2; ++a)
                vaB[c][a] = *(const short8*)(vfb + (size_t)(2 * k + 1) * 2048 + (a * 2 + c) * 512);
        #pragma unroll
        for (int c = 0; c < 2; ++c) {
            float shc[8];
            #pragma unroll
            for (int j = 0; j < 8; ++j) shc[j] = __shfl_xor(ps[16 + 8 * c + j], 32);
            short8 bfrag;
            #pragma unroll
            for (int j = 0; j < 8; ++j) {
                float pv;
                if (j < 4) pv = hi ? shc[4 + j]         : ps[16 + 8 * c + j];
                else       pv = hi ? ps[16 + 8 * c + j] : shc[j - 4];
                bfrag[j] = (short)f2bf(pv);
            }
            acc0 = __builtin_amdgcn_mfma_f32_32x32x16_bf16(vaB[c][0], bfrag, acc0, 0, 0, 0);
            acc1 = __builtin_amdgcn_mfma_f32_32x32x16_bf16(vaB[c][1], bfrag, acc1, 0, 0, 0);
        }

        {
            short8 pk0 = *(const short8*)&Pb2[sl][0 + 8 * hi];
            acc0 = __builtin_amdgcn_mfma_f32_32x32x16_bf16(eaA[0][0], pk0, acc0, 0, 0, 0);
            acc1 = __builtin_amdgcn_mfma_f32_32x32x16_bf16(eaA[0][1], pk0, acc1, 0, 0, 0);
            short8 pk1 = *(const short8*)&Pb2[sl][16 + 8 * hi];
            acc0 = __builtin_amdgcn_mfma_f32_32x32x16_bf16(eaA[1][0], pk1, acc0, 0, 0, 0);
            acc1 = __builtin_amdgcn_mfma_f32_32x32x16_bf16(eaA[1][1], pk1, acc1, 0, 0, 0);
            short8 pk2 = *(const short8*)&Pb2[sl][32 + 8 * hi];
            acc0 = __builtin_amdgcn_mfma_f32_32x32x16_bf16(eaB[0][0], pk2, acc0, 0, 0, 0);
            acc1 = __builtin_amdgcn_mfma_f32_32x32x16_bf16(eaB[0][1], pk2, acc1, 0, 0, 0);
            short8 pk3 = *(const short8*)&Pb2[sl][48 + 8 * hi];
            acc0 = __builtin_amdgcn_mfma_f32_32x32x16_bf16(eaB[1][0], pk3, acc0, 0, 0, 0);
            acc1 = __builtin_amdgcn_mfma_f32_32x32x16_bf16(eaB[1][1], pk3, acc1, 0, 0, 0);
            short8 pk4 = *(const short8*)&Pb2[sl][64 + 8 * hi];
            acc0 = __builtin_amdgcn_mfma_f32_32x32x16_bf16(eaC[0][0], pk4, acc0, 0, 0, 0);
            acc1 = __builtin_amdgcn_mfma_f32_32x32x16_bf16(eaC[0][1], pk4, acc1, 0, 0, 0);
            short8 pk5 = *(const short8*)&Pb2[sl][80 + 8 * hi];
            acc0 = __builtin_amdgcn_mfma_f32_32x32x16_bf16(eaC[1][0], pk5, acc0, 0, 0, 0);
            acc1 = __builtin_amdgcn_mfma_f32_32x32x16_bf16(eaC[1][1], pk5, acc1, 0, 0, 0);
        }
        __builtin_amdgcn_s_setprio(0);

        #pragma unroll
        for (int cc = 0; cc < 2; ++cc)
            #pragma unroll
            for (int a = 0; a < 2; ++a)
                eaA[cc][a] = eaC[cc][a];
    }

    // ================= trailing (1-2 tiles incl. diagonal) =================
    for (int i = i0; i <= st; ++i) {
        const int cb = (i - i0) * 32;
        const int t0 = i * 32;

        short8 kf[4], va[2][2];
        #pragma unroll
        for (int c = 0; c < 4; ++c)
            kf[c] = *(const short8*)(kfb + c * 16384 + (size_t)t0 * 16);
        #pragma unroll
        for (int c = 0; c < 2; ++c)
            #pragma unroll
            for (int a = 0; a < 2; ++a)
                va[c][a] = *(const short8*)(vfb + (size_t)i * 2048 + (a * 2 + c) * 512);

        f32x16 csw = {};
        __builtin_amdgcn_s_setprio(1);
        #pragma unroll
        for (int c = 0; c < 4; ++c)
            csw = __builtin_amdgcn_mfma_f32_32x32x16_bf16(kf[c], qf[c], csw, 0, 0, 0);
        __builtin_amdgcn_s_setprio(0);

        float sc[16];
        #pragma unroll
        for (int q = 0; q < 16; ++q) {
            const int trow = (q & 3) + 8 * (q >> 2) + 4 * hi;
            const int u = cb + trow + 31 - sl;
            sc[q] = (csw[q] + bf2f(Mpt[u][sl])) * 0.125f;
        }
        if (i == st) {
            #pragma unroll
            for (int q = 0; q < 16; ++q) {
                const int trow = (q & 3) + 8 * (q >> 2) + 4 * hi;
                if (t0 + trow > s0 + sl) sc[q] = -1e30f;
            }
        }
        float tm8[8], tm4[4];
        #pragma unroll
        for (int q = 0; q < 8; ++q) tm8[q] = fmaxf(sc[q], sc[q + 8]);
        #pragma unroll
        for (int q = 0; q < 4; ++q) tm4[q] = fmaxf(tm8[q], tm8[q + 4]);
        float tmax = fmaxf(fmaxf(tm4[0], tm4[1]), fmaxf(tm4[2], tm4[3]));
        tmax = fmaxf(tmax, __shfl_xor(tmax, 32));
        if (!__all(tmax <= mrow + 8.f)) {
            const float mnew = fmaxf(mrow, tmax);
            const float r = __expf(mrow - mnew);
            lrow *= r;
            acc0 *= r; acc1 *= r;
            mrow = mnew;
        }
        float ps[16];
        #pragma unroll
        for (int q = 0; q < 16; ++q) ps[q] = __expf(sc[q] - mrow);
        float ls8[8], ls4[4];
        #pragma unroll
        for (int q = 0; q < 8; ++q) ls8[q] = ps[q] + ps[q + 8];
        #pragma unroll
        for (int q = 0; q < 4; ++q) ls4[q] = ls8[q] + ls8[q + 4];
        float lsum = (ls4[0] + ls4[1]) + (ls4[2] + ls4[3]);
        lsum += __shfl_xor(lsum, 32);
        lrow += lsum;

        #pragma unroll
        for (int q = 0; q < 16; ++q) {
            const int trow = (q & 3) + 8 * (q >> 2) + 4 * hi;
            Pb2[sl][trow + 31 - sl] = f2bf(ps[q]);
        }
        if (i == i0 && Ppairs > 0) {
            #pragma unroll
            for (int jj = 0; jj < 16; ++jj)
                Pb2[sl][63 - sl + 16 * hi + jj] = 0;
        }

        __builtin_amdgcn_s_setprio(1);
        #pragma unroll
        for (int c = 0; c < 2; ++c) {
            float shc[8];
            #pragma unroll
            for (int j = 0; j < 8; ++j) shc[j] = __shfl_xor(ps[8 * c + j], 32);
            short8 bfrag;
            #pragma unroll
            for (int j = 0; j < 8; ++j) {
                float pv;
                if (j < 4) pv = hi ? shc[4 + j]    : ps[8 * c + j];
                else       pv = hi ? ps[8 * c + j] : shc[j - 4];
                bfrag[j] = (short)f2bf(pv);
            }
            acc0 = __builtin_amdgcn_mfma_f32_32x32x16_bf16(va[c][0], bfrag, acc0, 0, 0, 0);
            acc1 = __builtin_amdgcn_mfma_f32_32x32x16_bf16(va[c][1], bfrag, acc1, 0, 0, 0);
        }

        short8 eaF[2][2];
        #pragma unroll
        for (int cc = 0; cc < 2; ++cc)
            #pragma unroll
            for (int a = 0; a < 2; ++a)
                eaF[cc][a] = *(const short8*)(pevw + (size_t)(i + 1) * 2048 + cc * 1024 + a * 512);
        {
            short8 pk0 = *(const short8*)&Pb2[sl][0 + 8 * hi];
            acc0 = __builtin_amdgcn_mfma_f32_32x32x16_bf16(eaA[0][0], pk0, acc0, 0, 0, 0);
            acc1 = __builtin_amdgcn_mfma_f32_32x32x16_bf16(eaA[0][1], pk0, acc1, 0, 0, 0);
            short8 pk1 = *(const short8*)&Pb2[sl][16 + 8 * hi];
            acc0 = __builtin_amdgcn_mfma_f32_32x32x16_bf16(eaA[1][0], pk1, acc0, 0, 0, 0);
            acc1 = __builtin_amdgcn_mfma_f32_32x32x16_bf16(eaA[1][1], pk1, acc1, 0, 0, 0);
            short8 pk2 = *(const short8*)&Pb2[sl][32 + 8 * hi];
            acc0 = __builtin_amdgcn_mfma_f32_32x32x16_bf16(eaF[0][0], pk2, acc0, 0, 0, 0);
            acc1 = __builtin_amdgcn_mfma_f32_32x32x16_bf16(eaF[0][1], pk2, acc1, 0, 0, 0);
            short8 pk3 = *(const short8*)&Pb2[sl][48 + 8 * hi];
            acc0 = __builtin_amdgcn_mfma_f32_32x32x16_bf16(eaF[1][0], pk3, acc0, 0, 0, 0);
            acc1 = __builtin_amdgcn_mfma_f32_32x32x16_bf16(eaF[1][1], pk3, acc1, 0, 0, 0);
        }
        __builtin_amdgcn_s_setprio(0);

        #pragma unroll
        for (int cc = 0; cc < 2; ++cc)
            #pragma unroll
            for (int a = 0; a < 2; ++a)
                eaA[cc][a] = eaF[cc][a];
    }

    // ---- epilogue: bf16 packed stores ----
    const float inv = 1.0f / lrow;
    ushort* orow = AO + ((size_t)b * NS + s0 + sl) * NE + h * ND;
    #pragma unroll
    for (int g = 0; g < 4; ++g) {
        ushort4 o0 = make_ushort4(f2bf(acc0[4*g+0]*inv), f2bf(acc0[4*g+1]*inv),
                                  f2bf(acc0[4*g+2]*inv), f2bf(acc0[4*g+3]*inv));
        ushort4 o1 = make_ushort4(f2bf(acc1[4*g+0]*inv), f2bf(acc1[4*g+1]*inv),
                                  f2bf(acc1[4*g+2]*inv), f2bf(acc1[4*g+3]*inv));
        *(ushort4*)&orow[8 * g + 4 * hi]      = o0;
        *(ushort4*)&orow[8 * g + 4 * hi + 32] = o1;
    }
}

extern "C" void kernel_launch(void* const* d_in, const int* in_sizes, int n_in,
                              void* d_out, int out_size, void* d_ws, size_t ws_size,
                              hipStream_t stream) {
    const float* x   = (const float*)d_in[0];
    const float* Wq  = (const float*)d_in[2];
    const float* Wk  = (const float*)d_in[3];
    const float* Wv  = (const float*)d_in[4];
    const float* Wo  = (const float*)d_in[5];
    const float* pek = (const float*)d_in[6];
    const float* pev = (const float*)d_in[7];

    ushort* ws16 = (ushort*)d_ws;
    size_t off = 0;
    ushort* xb    = ws16 + off; off += (size_t)8388608;   // [8192,1024] bf16
    ushort* Wqb   = ws16 + off; off += (size_t)1048576;   // Wq|Wk|Wv|Wo contiguous
    ushort* Wkb   = ws16 + off; off += (size_t)1048576;
    ushort* Wvb   = ws16 + off; off += (size_t)1048576;
    ushort* Wob   = ws16 + off; off += (size_t)1048576;
    ushort* Qb    = ws16 + off; off += (size_t)8388608;   // Q row-major | K fm | V fm contiguous
    ushort* Kfm   = ws16 + off; off += (size_t)8388608;
    ushort* Vfm   = ws16 + off; off += (size_t)8388608;
    ushort* PEKf  = ws16 + off; off += (size_t)131136;
    ushort* PEVf  = ws16 + off; off += (size_t)67584;
    ushort* aob   = ws16 + off; off += (size_t)8388608;   // [B,S,E] bf16
    float*  out   = (float*)d_out;
    (void)Wkb; (void)Wvb; (void)Kfm; (void)Vfm;

    dim3 blk(256);
    // merged casts: x (8192 blocks) + W4 (4096) + pe (777)
    cast_all<<<dim3(12288 + (198720 + 255) / 256), blk, 0, stream>>>(
        x, Wq, Wk, Wv, Wo, pek, pev, xb, Wqb, PEKf, PEVf);

    // merged Q/K/V projection: N = 3072 (Wq|Wk|Wv), epilogue by segment
    gemm_mfma<5><<<dim3(64, 24), blk, 0, stream>>>(xb, Wqb, nullptr, Qb);

    attn_mfma<<<dim3(4096), dim3(64), 0, stream>>>(Qb, Qb + 8388608, Qb + 16777216,
                                                   PEKf, PEVf, aob);

    gemm_mfma<1><<<dim3(64, 8), blk, 0, stream>>>(aob, Wob, out, nullptr);
}

// Round 24
// 204.201 us; speedup vs baseline: 1.0038x; 1.0038x over previous
//
#include <hip/hip_runtime.h>
#include <math.h>
#include <string.h>

#define NB 8
#define NS 1024
#define NE 1024
#define NH 16
#define ND 64
#define NL 1024

typedef __attribute__((ext_vector_type(8))) short short8;
typedef __attribute__((ext_vector_type(4))) float f32x4;
typedef __attribute__((ext_vector_type(16))) float f32x16;

// native HW bf16 conversion (v_cvt on gfx950, RNE)
__device__ __forceinline__ ushort f2bf(float f) {
    union { __bf16 h; ushort u; } v;
    v.h = (__bf16)f;
    return v.u;
}
__device__ __forceinline__ float bf2f(ushort u) {
    union { unsigned u; float f; } v; v.u = ((unsigned)u) << 16;
    return v.f;
}

__device__ __forceinline__ void stage16(const ushort* gsrc, ushort* lbase) {
    __builtin_amdgcn_global_load_lds((const __attribute__((address_space(1))) void*)gsrc,
                                     (__attribute__((address_space(3))) void*)lbase,
                                     16, 0, 0);
}

// ---------------- merged cast kernel ----------------
// blocks [0,8192): x float4 -> bf16x4
// blocks [8192,12288): W4 float4 -> bf16x4 (Wq|Wk|Wv|Wo)
// blocks [12288,...): PEK + PEV fragment-major scalars
__global__ __launch_bounds__(256)
void cast_all(const float* __restrict__ x,
              const float* __restrict__ Wq, const float* __restrict__ Wk,
              const float* __restrict__ Wv, const float* __restrict__ Wo,
              const float* __restrict__ pek, const float* __restrict__ pev,
              ushort* __restrict__ xb, ushort* __restrict__ Wqb,
              ushort* __restrict__ outK, ushort* __restrict__ outV) {
    const int blk = blockIdx.x;
    if (blk < 8192) {
        int i = blk * 256 + threadIdx.x;
        float4 v = ((const float4*)x)[i];
        ((ushort4*)xb)[i] = make_ushort4(f2bf(v.x), f2bf(v.y), f2bf(v.z), f2bf(v.w));
    } else if (blk < 12288) {
        int i = (blk - 8192) * 256 + threadIdx.x;   // [0, 4*262144)
        const int seg = i >> 18, j = i & 262143;
        const float* src = seg == 0 ? Wq : seg == 1 ? Wk : seg == 2 ? Wv : Wo;
        float4 v = ((const float4*)src)[j];
        ((ushort4*)Wqb)[i] = make_ushort4(f2bf(v.x), f2bf(v.y), f2bf(v.z), f2bf(v.w));
    } else {
        int i = (blk - 12288) * 256 + threadIdx.x;
        if (i < 2049 * 64) {
            const int r = i >> 6, d = i & 63;
            outK[(size_t)(d >> 4) * 32784 + (size_t)r * 16 + (d & 15)] = f2bf(pek[i]);
        } else {
            int ii = i - 2049 * 64;
            if (ii >= 64 * 1056) return;
            const int d = ii / 1056, r = ii % 1056;
            const int m = r >> 5, cc = (r >> 4) & 1, hi = (r >> 3) & 1, j = r & 7;
            const int a = d >> 5, sl = d & 31;
            outV[(size_t)m * 2048 + cc * 1024 + a * 512 + (sl * 2 + hi) * 8 + j] =
                f2bf(pev[(size_t)(r + 1) * ND + d]);
        }
    }
}

// ---------------- MFMA GEMM: C = A @ W^T (bf16 in, fp32 acc) ----------------
// MODE 1: fp32 row-major [M,1024]                         (out-proj)
// MODE 5: merged QKV epilogue, N=3072; block-uniform seg = n0>>10:
//   seg 0 -> Q bf16 row-major [B,H,S,D]
//   seg 1 -> K fragment-major
//   seg 2 -> V fragment-major
template<int MODE>
__global__ __launch_bounds__(256)
void gemm_mfma(const ushort* __restrict__ A, const ushort* __restrict__ W,
               float* __restrict__ Cf, ushort* __restrict__ Cb)
{
    constexpr int K = 1024;
    __shared__ __align__(16) ushort As[128 * 32];
    __shared__ __align__(16) ushort Bs[128 * 32];
    const int tid = threadIdx.x;
    const int w   = tid >> 6;
    const int l   = tid & 63;
    const int m0  = blockIdx.x * 128;
    const int n0  = blockIdx.y * 128;
    const int wr  = w >> 1, wc = w & 1;

    const int srow = 16 * w + (l >> 2);
    const int scol = (l & 3) * 8;
    const ushort* aptr = A + (size_t)(m0 + srow) * K + scol;
    const ushort* bptr = W + (size_t)(n0 + srow) * K + scol;
    ushort* asl = &As[w * 512];
    ushort* bsl = &Bs[w * 512];

    const int fl = l & 15, fk = (l >> 4) * 8;

    f32x4 acc[4][4] = {};

    for (int k0 = 0; k0 < K; k0 += 32) {
        __syncthreads();
        stage16(aptr + k0,                    asl);
        stage16(aptr + k0 + (size_t)64 * K,   asl + 2048);
        stage16(bptr + k0,                    bsl);
        stage16(bptr + k0 + (size_t)64 * K,   bsl + 2048);
        __syncthreads();

        short8 af[4], bf[4];
        #pragma unroll
        for (int i = 0; i < 4; ++i)
            af[i] = *(const short8*)&As[(wr * 64 + i * 16 + fl) * 32 + fk];
        #pragma unroll
        for (int j = 0; j < 4; ++j)
            bf[j] = *(const short8*)&Bs[(wc * 64 + j * 16 + fl) * 32 + fk];
        #pragma unroll
        for (int i = 0; i < 4; ++i)
            #pragma unroll
            for (int j = 0; j < 4; ++j)
                acc[i][j] = __builtin_amdgcn_mfma_f32_16x16x32_bf16(af[i], bf[j], acc[i][j], 0, 0, 0);
    }

    #pragma unroll
    for (int i = 0; i < 4; ++i) {
        #pragma unroll
        for (int j = 0; j < 4; ++j) {
            #pragma unroll
            for (int q = 0; q < 4; ++q) {
                const int m = m0 + wr * 64 + i * 16 + (l >> 4) * 4 + q;
                const int n = n0 + wc * 64 + j * 16 + fl;
                const float vv = acc[i][j][q];
                if (MODE == 5) {
                    const int seg = n0 >> 10;        // block-uniform
                    const int nn  = n & 1023;
                    const int b = m >> 10, s = m & 1023;
                    const int h = nn >> 6, d = nn & 63;
                    const int bh = b * NH + h;
                    if (seg == 0) {
                        Cb[(((size_t)bh) * NS + s) * ND + d] = f2bf(vv);
                    } else if (seg == 1) {
                        (Cb + (size_t)8388608)
                            [((size_t)bh * 4 + (d >> 4)) * 16384 + (size_t)s * 16 + (d & 15)] = f2bf(vv);
                    } else {
                        const int it = s >> 5, trel = s & 31;
                        const int c = trel >> 4, hi2 = (trel >> 3) & 1, jj = trel & 7;
                        const int a = d >> 5, sl2 = d & 31;
                        (Cb + (size_t)16777216)
                            [(size_t)bh * 65536 + it * 2048 +
                             ((a * 2 + c) * 64 + sl2 * 2 + hi2) * 8 + jj] = f2bf(vv);
                    }
                } else {
                    Cf[(size_t)m * NE + n] = vv;
                }
            }
        }
    }
}

// ---------------- MFMA fused attention with RPE ----------------
// Round-22 verified body + K prefetch restored (round-13 pattern on the
// pair loop): kf tiles loaded in prologue, reloaded into the SAME registers
// right after the QK MFMAs consume them -> next window's K has a full
// softmax+PV+skew of latency cover. Trailing consumes the final prefetch.
__global__ __launch_bounds__(64, 2)
void attn_mfma(const ushort* __restrict__ Qb, const ushort* __restrict__ Kf_,
               const ushort* __restrict__ Vf_, const ushort* __restrict__ PEKf,
               const ushort* __restrict__ PEVf, ushort* __restrict__ AO)
{
    const int idx = blockIdx.x;
    const int st  = 31 - (idx >> 7);     // longest blocks first
    const int bh  = idx & 127;
    const int b   = bh >> 4, h = bh & 15;
    const int n2  = h * NB + b;          // torch view(S,H,B,S).transpose(0,2) shuffle
    const int b2  = n2 >> 4, h2 = n2 & 15;
    const int s0  = st * 32;

    const int lane = threadIdx.x;
    const int sl   = lane & 31;
    const int hi   = lane >> 5;

    const int T      = st + 1;
    const int Ppairs = (T - 1) >> 1;     // unmasked pairs
    const int i0     = 2 * Ppairs;       // first trailing tile (1 or 2 trail)

    __shared__ __align__(16) ushort Mpt[96][34];   // [u][s], stride 34 (68B) — 6528 B
    __shared__ __align__(16) ushort Pb2[32][98];   // 6272 B

    for (int t = lane; t < 32 * 98 / 2; t += 64) ((int*)Pb2)[t] = 0;

    const ushort* qptr  = Qb + (((size_t)bh * NS) + s0 + sl) * ND + hi * 8;
    const ushort* q2ptr = Qb + ((((size_t)b2 * NH + h2) * NS) + s0 + sl) * ND + hi * 8;
    short8 qf[4], q2f[4];
    #pragma unroll
    for (int c = 0; c < 4; ++c) {
        qf[c]  = *(const short8*)(qptr  + 16 * c);
        q2f[c] = *(const short8*)(q2ptr + 16 * c);
    }

    const ushort* kfb  = Kf_ + (size_t)bh * 65536 + sl * 16 + hi * 8;
    const ushort* vfb  = Vf_ + (size_t)bh * 65536 + (sl * 2 + hi) * 8;
    const ushort* efb  = PEKf + sl * 16 + hi * 8;
    const ushort* pevw = PEVf + (size_t)(31 - st) * 2048 + (sl * 2 + hi) * 8;
    const int RBASE = NL - 31 - s0;

    // chunk c -> Mpt[cb+sl][*]; packed b32 writes via memcpy (alias-safe)
    auto mpchunk = [&](int c, int cb) {
        f32x16 cm = {};
        #pragma unroll
        for (int c4 = 0; c4 < 4; ++c4) {
            short8 ef = *(const short8*)(efb + (size_t)c4 * 32784 +
                                         (size_t)(RBASE + 32 * c) * 16);
            cm = __builtin_amdgcn_mfma_f32_32x32x16_bf16(q2f[c4], ef, cm, 0, 0, 0);
        }
        #pragma unroll
        for (int w2 = 0; w2 < 8; ++w2) {
            const int q = 2 * w2;
            const int srow = (q & 3) + 8 * (q >> 2) + 4 * hi;   // even
            unsigned pk = (unsigned)f2bf(cm[q]) | ((unsigned)f2bf(cm[q + 1]) << 16);
            __builtin_memcpy(&Mpt[cb + sl][srow], &pk, 4);
        }
    };

    f32x16 acc0 = {}, acc1 = {};
    float mrow = -1e30f, lrow = 0.f;
    short8 eaA[2][2];
    short8 kfA[4], kfB[4];   // K prefetch registers (tiles 2k, 2k+1)

    __builtin_amdgcn_s_setprio(1);
    mpchunk(0, 0);
    mpchunk(1, 32);
    mpchunk(2, 64);
    __builtin_amdgcn_s_setprio(0);
    #pragma unroll
    for (int cc = 0; cc < 2; ++cc)
        #pragma unroll
        for (int a = 0; a < 2; ++a)
            eaA[cc][a] = *(const short8*)(pevw + cc * 1024 + a * 512);
    // prologue K prefetch: tiles 0 and 1 (tile 1 address always in-bounds)
    #pragma unroll
    for (int c = 0; c < 4; ++c) {
        kfA[c] = *(const short8*)(kfb + c * 16384);
        kfB[c] = *(const short8*)(kfb + c * 16384 + 32 * 16);
    }

    // ================= pair loop =================
    for (int k = 0; k < Ppairs; ++k) {
        const int t0 = 64 * k;

        short8 vaA[2][2];
        #pragma unroll
        for (int c = 0; c < 2; ++c)
            #pragma unroll
            for (int a = 0; a < 2; ++a)
                vaA[c][a] = *(const short8*)(vfb + (size_t)(2 * k) * 2048 + (a * 2 + c) * 512);

        f32x16 csw0 = {}, csw1 = {};
        __builtin_amdgcn_s_setprio(1);
        #pragma unroll
        for (int c = 0; c < 4; ++c)
            csw0 = __builtin_amdgcn_mfma_f32_32x32x16_bf16(kfA[c], qf[c], csw0, 0, 0, 0);
        #pragma unroll
        for (int c = 0; c < 4; ++c)
            csw1 = __builtin_amdgcn_mfma_f32_32x32x16_bf16(kfB[c], qf[c], csw1, 0, 0, 0);
        __builtin_amdgcn_s_setprio(0);

        // post-consumption K reload for next window (tiles 2k+2, 2k+3;
        // addresses always in-bounds; trailing loop consumes the last one)
        #pragma unroll
        for (int c = 0; c < 4; ++c) {
            kfA[c] = *(const short8*)(kfb + c * 16384 + (size_t)(t0 + 64) * 16);
            kfB[c] = *(const short8*)(kfb + c * 16384 + (size_t)(t0 + 96) * 16);
        }

        float sc[32];
        #pragma unroll
        for (int q = 0; q < 16; ++q) {
            const int trow = (q & 3) + 8 * (q >> 2) + 4 * hi;
            const int u = trow + 31 - sl;
            sc[q]      = (csw0[q] + bf2f(Mpt[u][sl]))      * 0.125f;
            sc[16 + q] = (csw1[q] + bf2f(Mpt[u + 32][sl])) * 0.125f;
        }

        float tm16[16], tm8[8], tm4[4];
        #pragma unroll
        for (int q = 0; q < 16; ++q) tm16[q] = fmaxf(sc[q], sc[q + 16]);
        #pragma unroll
        for (int q = 0; q < 8; ++q) tm8[q] = fmaxf(tm16[q], tm16[q + 8]);
        #pragma unroll
        for (int q = 0; q < 4; ++q) tm4[q] = fmaxf(tm8[q], tm8[q + 4]);
        float tmax = fmaxf(fmaxf(tm4[0], tm4[1]), fmaxf(tm4[2], tm4[3]));
        tmax = fmaxf(tmax, __shfl_xor(tmax, 32));
        if (!__all(tmax <= mrow + 8.f)) {
            const float mnew = fmaxf(mrow, tmax);
            const float r = __expf(mrow - mnew);
            lrow *= r;
            acc0 *= r; acc1 *= r;
            mrow = mnew;
        }
        float ps[32];
        #pragma unroll
        for (int q = 0; q < 32; ++q) ps[q] = __expf(sc[q] - mrow);
        float ls16[16], ls8[8], ls4[4];
        #pragma unroll
        for (int q = 0; q < 16; ++q) ls16[q] = ps[q] + ps[q + 16];
        #pragma unroll
        for (int q = 0; q < 8; ++q) ls8[q] = ls16[q] + ls16[q + 8];
        #pragma unroll
        for (int q = 0; q < 4; ++q) ls4[q] = ls8[q] + ls8[q + 4];
        float lsum = (ls4[0] + ls4[1]) + (ls4[2] + ls4[3]);
        lsum += __shfl_xor(lsum, 32);
        lrow += lsum;

        #pragma unroll
        for (int q = 0; q < 16; ++q) {
            const int trow = (q & 3) + 8 * (q >> 2) + 4 * hi;
            Pb2[sl][trow + 31 - sl] = f2bf(ps[q]);
            Pb2[sl][trow + 63 - sl] = f2bf(ps[16 + q]);
        }

        // window k+1 chunks overwrite the single buffer AFTER this window's
        // gather reads (memcpy writes alias-order vs the ushort reads)
        __builtin_amdgcn_s_setprio(1);
        mpchunk(2 * k + 2, 0);
        mpchunk(2 * k + 3, 32);
        mpchunk(2 * k + 4, 64);
        __builtin_amdgcn_s_setprio(0);

        short8 eaB[2][2], eaC[2][2];
        #pragma unroll
        for (int cc = 0; cc < 2; ++cc)
            #pragma unroll
            for (int a = 0; a < 2; ++a) {
                eaB[cc][a] = *(const short8*)(pevw + (size_t)(2 * k + 1) * 2048 + cc * 1024 + a * 512);
                eaC[cc][a] = *(const short8*)(pevw + (size_t)(2 * k + 2) * 2048 + cc * 1024 + a * 512);
            }

        __builtin_amdgcn_s_setprio(1);
        #pragma unroll
        for (int c = 0; c < 2; ++c) {
            float shc[8];
            #pragma unroll
            for (int j = 0; j < 8; ++j) shc[j] = __shfl_xor(ps[8 * c + j], 32);
            short8 bfrag;
            #pragma unroll
            for (int j = 0; j < 8; ++j) {
                float pv;
                if (j < 4) pv = hi ? shc[4 + j]    : ps[8 * c + j];
                else       pv = hi ? ps[8 * c + j] : shc[j - 4];
                bfrag[j] = (short)f2bf(pv);
            }
            acc0 = __builtin_amdgcn_mfma_f32_32x32x16_bf16(vaA[c][0], bfrag, acc0, 0, 0, 0);
            acc1 = __builtin_amdgcn_mfma_f32_32x32x16_bf16(vaA[c][1], bfrag, acc1, 0, 0, 0);
        }
        short8 vaB[2][2];
        #pragma unroll
        for (int c = 0; c < 2; ++c)
            #pragma unroll
            for (int a = 0; a < 2; ++a)
                vaB[c][a] = *(const short8*)(vfb + (size_t)(2 * k + 1) * 2048 + (a * 2 + c) * 512);
        #pragma unroll
        for (int c = 0; c < 2; ++c) {
            float shc[8];
            #pragma unroll
            for (int j = 0; j < 8; ++j) shc[j] = __shfl_xor(ps[16 + 8 * c + j], 32);
            short8 bfrag;
            #pragma unroll
            for (int j = 0; j < 8; ++j) {
                float pv;
                if (j < 4) pv = hi ? shc[4 + j]         : ps[16 + 8 * c + j];
                else       pv = hi ? ps[16 + 8 * c + j] : shc[j - 4];
                bfrag[j] = (short)f2bf(pv);
            }
            acc0 = __builtin_amdgcn_mfma_f32_32x32x16_bf16(vaB[c][0], bfrag, acc0, 0, 0, 0);
            acc1 = __builtin_amdgcn_mfma_f32_32x32x16_bf16(vaB[c][1], bfrag, acc1, 0, 0, 0);
        }

        {
            short8 pk0 = *(const short8*)&Pb2[sl][0 + 8 * hi];
            acc0 = __builtin_amdgcn_mfma_f32_32x32x16_bf16(eaA[0][0], pk0, acc0, 0, 0, 0);
            acc1 = __builtin_amdgcn_mfma_f32_32x32x16_bf16(eaA[0][1], pk0, acc1, 0, 0, 0);
            short8 pk1 = *(const short8*)&Pb2[sl][16 + 8 * hi];
            acc0 = __builtin_amdgcn_mfma_f32_32x32x16_bf16(eaA[1][0], pk1, acc0, 0, 0, 0);
            acc1 = __builtin_amdgcn_mfma_f32_32x32x16_bf16(eaA[1][1], pk1, acc1, 0, 0, 0);
            short8 pk2 = *(const short8*)&Pb2[sl][32 + 8 * hi];
            acc0 = __builtin_amdgcn_mfma_f32_32x32x16_bf16(eaB[0][0], pk2, acc0, 0, 0, 0);
            acc1 = __builtin_amdgcn_mfma_f32_32x32x16_bf16(eaB[0][1], pk2, acc1, 0, 0, 0);
            short8 pk3 = *(const short8*)&Pb2[sl][48 + 8 * hi];
            acc0 = __builtin_amdgcn_mfma_f32_32x32x16_bf16(eaB[1][0], pk3, acc0, 0, 0, 0);
            acc1 = __builtin_amdgcn_mfma_f32_32x32x16_bf16(eaB[1][1], pk3, acc1, 0, 0, 0);
            short8 pk4 = *(const short8*)&Pb2[sl][64 + 8 * hi];
            acc0 = __builtin_amdgcn_mfma_f32_32x32x16_bf16(eaC[0][0], pk4, acc0, 0, 0, 0);
            acc1 = __builtin_amdgcn_mfma_f32_32x32x16_bf16(eaC[0][1], pk4, acc1, 0, 0, 0);
            short8 pk5 = *(const short8*)&Pb2[sl][80 + 8 * hi];
            acc0 = __builtin_amdgcn_mfma_f32_32x32x16_bf16(eaC[1][0], pk5, acc0, 0, 0, 0);
            acc1 = __builtin_amdgcn_mfma_f32_32x32x16_bf16(eaC[1][1], pk5, acc1, 0, 0, 0);
        }
        __builtin_amdgcn_s_setprio(0);

        #pragma unroll
        for (int cc = 0; cc < 2; ++cc)
            #pragma unroll
            for (int a = 0; a < 2; ++a)
                eaA[cc][a] = eaC[cc][a];
    }

    // ================= trailing (1-2 tiles incl. diagonal) =================
    for (int i = i0; i <= st; ++i) {
        const int cb = (i - i0) * 32;
        const int t0 = i * 32;

        short8 kf[4], va[2][2];
        #pragma unroll
        for (int c = 0; c < 4; ++c)
            kf[c] = (i == i0) ? kfA[c] : kfB[c];   // consume final prefetch
        #pragma unroll
        for (int c = 0; c < 2; ++c)
            #pragma unroll
            for (int a = 0; a < 2; ++a)
                va[c][a] = *(const short8*)(vfb + (size_t)i * 2048 + (a * 2 + c) * 512);

        f32x16 csw = {};
        __builtin_amdgcn_s_setprio(1);
        #pragma unroll
        for (int c = 0; c < 4; ++c)
            csw = __builtin_amdgcn_mfma_f32_32x32x16_bf16(kf[c], qf[c], csw, 0, 0, 0);
        __builtin_amdgcn_s_setprio(0);

        float sc[16];
        #pragma unroll
        for (int q = 0; q < 16; ++q) {
            const int trow = (q & 3) + 8 * (q >> 2) + 4 * hi;
            const int u = cb + trow + 31 - sl;
            sc[q] = (csw[q] + bf2f(Mpt[u][sl])) * 0.125f;
        }
        if (i == st) {
            #pragma unroll
            for (int q = 0; q < 16; ++q) {
                const int trow = (q & 3) + 8 * (q >> 2) + 4 * hi;
                if (t0 + trow > s0 + sl) sc[q] = -1e30f;
            }
        }
        float tm8[8], tm4[4];
        #pragma unroll
        for (int q = 0; q < 8; ++q) tm8[q] = fmaxf(sc[q], sc[q + 8]);
        #pragma unroll
        for (int q = 0; q < 4; ++q) tm4[q] = fmaxf(tm8[q], tm8[q + 4]);
        float tmax = fmaxf(fmaxf(tm4[0], tm4[1]), fmaxf(tm4[2], tm4[3]));
        tmax = fmaxf(tmax, __shfl_xor(tmax, 32));
        if (!__all(tmax <= mrow + 8.f)) {
            const float mnew = fmaxf(mrow, tmax);
            const float r = __expf(mrow - mnew);
            lrow *= r;
            acc0 *= r; acc1 *= r;
            mrow = mnew;
        }
        float ps[16];
        #pragma unroll
        for (int q = 0; q < 16; ++q) ps[q] = __expf(sc[q] - mrow);
        float ls8[8], ls4[4];
        #pragma unroll
        for (int q = 0; q < 8; ++q) ls8[q] = ps[q] + ps[q + 8];
        #pragma unroll
        for (int q = 0; q < 4; ++q) ls4[q] = ls8[q] + ls8[q + 4];
        float lsum = (ls4[0] + ls4[1]) + (ls4[2] + ls4[3]);
        lsum += __shfl_xor(lsum, 32);
        lrow += lsum;

        #pragma unroll
        for (int q = 0; q < 16; ++q) {
            const int trow = (q & 3) + 8 * (q >> 2) + 4 * hi;
            Pb2[sl][trow + 31 - sl] = f2bf(ps[q]);
        }
        if (i == i0 && Ppairs > 0) {
            #pragma unroll
            for (int jj = 0; jj < 16; ++jj)
                Pb2[sl][63 - sl + 16 * hi + jj] = 0;
        }

        __builtin_amdgcn_s_setprio(1);
        #pragma unroll
        for (int c = 0; c < 2; ++c) {
            float shc[8];
            #pragma unroll
            for (int j = 0; j < 8; ++j) shc[j] = __shfl_xor(ps[8 * c + j], 32);
            short8 bfrag;
            #pragma unroll
            for (int j = 0; j < 8; ++j) {
                float pv;
                if (j < 4) pv = hi ? shc[4 + j]    : ps[8 * c + j];
                else       pv = hi ? ps[8 * c + j] : shc[j - 4];
                bfrag[j] = (short)f2bf(pv);
            }
            acc0 = __builtin_amdgcn_mfma_f32_32x32x16_bf16(va[c][0], bfrag, acc0, 0, 0, 0);
            acc1 = __builtin_amdgcn_mfma_f32_32x32x16_bf16(va[c][1], bfrag, acc1, 0, 0, 0);
        }

        short8 eaF[2][2];
        #pragma unroll
        for (int cc = 0; cc < 2; ++cc)
            #pragma unroll
            for (int a = 0; a < 2; ++a)
                eaF[cc][a] = *(const short8*)(pevw + (size_t)(i + 1) * 2048 + cc * 1024 + a * 512);
        {
            short8 pk0 = *(const short8*)&Pb2[sl][0 + 8 * hi];
            acc0 = __builtin_amdgcn_mfma_f32_32x32x16_bf16(eaA[0][0], pk0, acc0, 0, 0, 0);
            acc1 = __builtin_amdgcn_mfma_f32_32x32x16_bf16(eaA[0][1], pk0, acc1, 0, 0, 0);
            short8 pk1 = *(const short8*)&Pb2[sl][16 + 8 * hi];
            acc0 = __builtin_amdgcn_mfma_f32_32x32x16_bf16(eaA[1][0], pk1, acc0, 0, 0, 0);
            acc1 = __builtin_amdgcn_mfma_f32_32x32x16_bf16(eaA[1][1], pk1, acc1, 0, 0, 0);
            short8 pk2 = *(const short8*)&Pb2[sl][32 + 8 * hi];
            acc0 = __builtin_amdgcn_mfma_f32_32x32x16_bf16(eaF[0][0], pk2, acc0, 0, 0, 0);
            acc1 = __builtin_amdgcn_mfma_f32_32x32x16_bf16(eaF[0][1], pk2, acc1, 0, 0, 0);
            short8 pk3 = *(const short8*)&Pb2[sl][48 + 8 * hi];
            acc0 = __builtin_amdgcn_mfma_f32_32x32x16_bf16(eaF[1][0], pk3, acc0, 0, 0, 0);
            acc1 = __builtin_amdgcn_mfma_f32_32x32x16_bf16(eaF[1][1], pk3, acc1, 0, 0, 0);
        }
        __builtin_amdgcn_s_setprio(0);

        #pragma unroll
        for (int cc = 0; cc < 2; ++cc)
            #pragma unroll
            for (int a = 0; a < 2; ++a)
                eaA[cc][a] = eaF[cc][a];
    }

    // ---- epilogue: bf16 packed stores ----
    const float inv = 1.0f / lrow;
    ushort* orow = AO + ((size_t)b * NS + s0 + sl) * NE + h * ND;
    #pragma unroll
    for (int g = 0; g < 4; ++g) {
        ushort4 o0 = make_ushort4(f2bf(acc0[4*g+0]*inv), f2bf(acc0[4*g+1]*inv),
                                  f2bf(acc0[4*g+2]*inv), f2bf(acc0[4*g+3]*inv));
        ushort4 o1 = make_ushort4(f2bf(acc1[4*g+0]*inv), f2bf(acc1[4*g+1]*inv),
                                  f2bf(acc1[4*g+2]*inv), f2bf(acc1[4*g+3]*inv));
        *(ushort4*)&orow[8 * g + 4 * hi]      = o0;
        *(ushort4*)&orow[8 * g + 4 * hi + 32] = o1;
    }
}

extern "C" void kernel_launch(void* const* d_in, const int* in_sizes, int n_in,
                              void* d_out, int out_size, void* d_ws, size_t ws_size,
                              hipStream_t stream) {
    const float* x   = (const float*)d_in[0];
    const float* Wq  = (const float*)d_in[2];
    const float* Wk  = (const float*)d_in[3];
    const float* Wv  = (const float*)d_in[4];
    const float* Wo  = (const float*)d_in[5];
    const float* pek = (const float*)d_in[6];
    const float* pev = (const float*)d_in[7];

    ushort* ws16 = (ushort*)d_ws;
    size_t off = 0;
    ushort* xb    = ws16 + off; off += (size_t)8388608;   // [8192,1024] bf16
    ushort* Wqb   = ws16 + off; off += (size_t)1048576;   // Wq|Wk|Wv|Wo contiguous
    ushort* Wkb   = ws16 + off; off += (size_t)1048576;
    ushort* Wvb   = ws16 + off; off += (size_t)1048576;
    ushort* Wob   = ws16 + off; off += (size_t)1048576;
    ushort* Qb    = ws16 + off; off += (size_t)8388608;   // Q row-major | K fm | V fm contiguous
    ushort* Kfm   = ws16 + off; off += (size_t)8388608;
    ushort* Vfm   = ws16 + off; off += (size_t)8388608;
    ushort* PEKf  = ws16 + off; off += (size_t)131136;
    ushort* PEVf  = ws16 + off; off += (size_t)67584;
    ushort* aob   = ws16 + off; off += (size_t)8388608;   // [B,S,E] bf16
    float*  out   = (float*)d_out;
    (void)Wkb; (void)Wvb; (void)Kfm; (void)Vfm;

    dim3 blk(256);
    // merged casts: x (8192 blocks) + W4 (4096) + pe (777)
    cast_all<<<dim3(12288 + (198720 + 255) / 256), blk, 0, stream>>>(
        x, Wq, Wk, Wv, Wo, pek, pev, xb, Wqb, PEKf, PEVf);

    // merged Q/K/V projection: N = 3072 (Wq|Wk|Wv), epilogue by segment
    gemm_mfma<5><<<dim3(64, 24), blk, 0, stream>>>(xb, Wqb, nullptr, Qb);

    attn_mfma<<<dim3(4096), dim3(64), 0, stream>>>(Qb, Qb + 8388608, Qb + 16777216,
                                                   PEKf, PEVf, aob);

    gemm_mfma<1><<<dim3(64, 8), blk, 0, stream>>>(aob, Wob, out, nullptr);
}

// Round 25
// 203.368 us; speedup vs baseline: 1.0079x; 1.0041x over previous
//
#include <hip/hip_runtime.h>
#include <math.h>
#include <string.h>

#define NB 8
#define NS 1024
#define NE 1024
#define NH 16
#define ND 64
#define NL 1024

typedef __attribute__((ext_vector_type(8))) short short8;
typedef __attribute__((ext_vector_type(4))) float f32x4;
typedef __attribute__((ext_vector_type(16))) float f32x16;

// native HW bf16 conversion (v_cvt on gfx950, RNE)
__device__ __forceinline__ ushort f2bf(float f) {
    union { __bf16 h; ushort u; } v;
    v.h = (__bf16)f;
    return v.u;
}
__device__ __forceinline__ float bf2f(ushort u) {
    union { unsigned u; float f; } v; v.u = ((unsigned)u) << 16;
    return v.f;
}

__device__ __forceinline__ void stage16(const ushort* gsrc, ushort* lbase) {
    __builtin_amdgcn_global_load_lds((const __attribute__((address_space(1))) void*)gsrc,
                                     (__attribute__((address_space(3))) void*)lbase,
                                     16, 0, 0);
}

// ---------------- merged cast kernel ----------------
// blocks [0,8192): x float4 -> bf16x4
// blocks [8192,12288): W4 float4 -> bf16x4 (Wq|Wk|Wv|Wo)
// blocks [12288,...): PEK + PEV fragment-major scalars
__global__ __launch_bounds__(256)
void cast_all(const float* __restrict__ x,
              const float* __restrict__ Wq, const float* __restrict__ Wk,
              const float* __restrict__ Wv, const float* __restrict__ Wo,
              const float* __restrict__ pek, const float* __restrict__ pev,
              ushort* __restrict__ xb, ushort* __restrict__ Wqb,
              ushort* __restrict__ outK, ushort* __restrict__ outV) {
    const int blk = blockIdx.x;
    if (blk < 8192) {
        int i = blk * 256 + threadIdx.x;
        float4 v = ((const float4*)x)[i];
        ((ushort4*)xb)[i] = make_ushort4(f2bf(v.x), f2bf(v.y), f2bf(v.z), f2bf(v.w));
    } else if (blk < 12288) {
        int i = (blk - 8192) * 256 + threadIdx.x;   // [0, 4*262144)
        const int seg = i >> 18, j = i & 262143;
        const float* src = seg == 0 ? Wq : seg == 1 ? Wk : seg == 2 ? Wv : Wo;
        float4 v = ((const float4*)src)[j];
        ((ushort4*)Wqb)[i] = make_ushort4(f2bf(v.x), f2bf(v.y), f2bf(v.z), f2bf(v.w));
    } else {
        int i = (blk - 12288) * 256 + threadIdx.x;
        if (i < 2049 * 64) {
            const int r = i >> 6, d = i & 63;
            outK[(size_t)(d >> 4) * 32784 + (size_t)r * 16 + (d & 15)] = f2bf(pek[i]);
        } else {
            int ii = i - 2049 * 64;
            if (ii >= 64 * 1056) return;
            const int d = ii / 1056, r = ii % 1056;
            const int m = r >> 5, cc = (r >> 4) & 1, hi = (r >> 3) & 1, j = r & 7;
            const int a = d >> 5, sl = d & 31;
            outV[(size_t)m * 2048 + cc * 1024 + a * 512 + (sl * 2 + hi) * 8 + j] =
                f2bf(pev[(size_t)(r + 1) * ND + d]);
        }
    }
}

// ---------------- MFMA GEMM: C = A @ W^T (bf16 in, fp32 acc) ----------------
// MODE 1: fp32 row-major [M,1024]                         (out-proj)
// MODE 5: merged QKV epilogue, N=3072; block-uniform seg = n0>>10:
//   seg 0 -> Q bf16 row-major [B,H,S,D]
//   seg 1 -> K fragment-major
//   seg 2 -> V fragment-major
template<int MODE>
__global__ __launch_bounds__(256)
void gemm_mfma(const ushort* __restrict__ A, const ushort* __restrict__ W,
               float* __restrict__ Cf, ushort* __restrict__ Cb)
{
    constexpr int K = 1024;
    __shared__ __align__(16) ushort As[128 * 32];
    __shared__ __align__(16) ushort Bs[128 * 32];
    const int tid = threadIdx.x;
    const int w   = tid >> 6;
    const int l   = tid & 63;
    const int m0  = blockIdx.x * 128;
    const int n0  = blockIdx.y * 128;
    const int wr  = w >> 1, wc = w & 1;

    const int srow = 16 * w + (l >> 2);
    const int scol = (l & 3) * 8;
    const ushort* aptr = A + (size_t)(m0 + srow) * K + scol;
    const ushort* bptr = W + (size_t)(n0 + srow) * K + scol;
    ushort* asl = &As[w * 512];
    ushort* bsl = &Bs[w * 512];

    const int fl = l & 15, fk = (l >> 4) * 8;

    f32x4 acc[4][4] = {};

    for (int k0 = 0; k0 < K; k0 += 32) {
        __syncthreads();
        stage16(aptr + k0,                    asl);
        stage16(aptr + k0 + (size_t)64 * K,   asl + 2048);
        stage16(bptr + k0,                    bsl);
        stage16(bptr + k0 + (size_t)64 * K,   bsl + 2048);
        __syncthreads();

        short8 af[4], bf[4];
        #pragma unroll
        for (int i = 0; i < 4; ++i)
            af[i] = *(const short8*)&As[(wr * 64 + i * 16 + fl) * 32 + fk];
        #pragma unroll
        for (int j = 0; j < 4; ++j)
            bf[j] = *(const short8*)&Bs[(wc * 64 + j * 16 + fl) * 32 + fk];
        #pragma unroll
        for (int i = 0; i < 4; ++i)
            #pragma unroll
            for (int j = 0; j < 4; ++j)
                acc[i][j] = __builtin_amdgcn_mfma_f32_16x16x32_bf16(af[i], bf[j], acc[i][j], 0, 0, 0);
    }

    #pragma unroll
    for (int i = 0; i < 4; ++i) {
        #pragma unroll
        for (int j = 0; j < 4; ++j) {
            #pragma unroll
            for (int q = 0; q < 4; ++q) {
                const int m = m0 + wr * 64 + i * 16 + (l >> 4) * 4 + q;
                const int n = n0 + wc * 64 + j * 16 + fl;
                const float vv = acc[i][j][q];
                if (MODE == 5) {
                    const int seg = n0 >> 10;        // block-uniform
                    const int nn  = n & 1023;
                    const int b = m >> 10, s = m & 1023;
                    const int h = nn >> 6, d = nn & 63;
                    const int bh = b * NH + h;
                    if (seg == 0) {
                        Cb[(((size_t)bh) * NS + s) * ND + d] = f2bf(vv);
                    } else if (seg == 1) {
                        (Cb + (size_t)8388608)
                            [((size_t)bh * 4 + (d >> 4)) * 16384 + (size_t)s * 16 + (d & 15)] = f2bf(vv);
                    } else {
                        const int it = s >> 5, trel = s & 31;
                        const int c = trel >> 4, hi2 = (trel >> 3) & 1, jj = trel & 7;
                        const int a = d >> 5, sl2 = d & 31;
                        (Cb + (size_t)16777216)
                            [(size_t)bh * 65536 + it * 2048 +
                             ((a * 2 + c) * 64 + sl2 * 2 + hi2) * 8 + jj] = f2bf(vv);
                    }
                } else {
                    Cf[(size_t)m * NE + n] = vv;
                }
            }
        }
    }
}

// ---------------- MFMA fused attention with RPE ----------------
// Round-22 verified body + register diet (NO launch-bounds change, so no
// spill risk): K prefetch reverted (was neutral, -12 regs); eaB/eaC loads
// deferred to just before their skew MFMAs (-16 peak regs). If unified
// demand lands <=170, HW occupancy rises to 3 waves/SIMD automatically.
__global__ __launch_bounds__(64, 2)
void attn_mfma(const ushort* __restrict__ Qb, const ushort* __restrict__ Kf_,
               const ushort* __restrict__ Vf_, const ushort* __restrict__ PEKf,
               const ushort* __restrict__ PEVf, ushort* __restrict__ AO)
{
    const int idx = blockIdx.x;
    const int st  = 31 - (idx >> 7);     // longest blocks first
    const int bh  = idx & 127;
    const int b   = bh >> 4, h = bh & 15;
    const int n2  = h * NB + b;          // torch view(S,H,B,S).transpose(0,2) shuffle
    const int b2  = n2 >> 4, h2 = n2 & 15;
    const int s0  = st * 32;

    const int lane = threadIdx.x;
    const int sl   = lane & 31;
    const int hi   = lane >> 5;

    const int T      = st + 1;
    const int Ppairs = (T - 1) >> 1;     // unmasked pairs
    const int i0     = 2 * Ppairs;       // first trailing tile (1 or 2 trail)

    __shared__ __align__(16) ushort Mpt[96][34];   // [u][s], stride 34 (68B) — 6528 B
    __shared__ __align__(16) ushort Pb2[32][98];   // 6272 B

    for (int t = lane; t < 32 * 98 / 2; t += 64) ((int*)Pb2)[t] = 0;

    const ushort* qptr  = Qb + (((size_t)bh * NS) + s0 + sl) * ND + hi * 8;
    const ushort* q2ptr = Qb + ((((size_t)b2 * NH + h2) * NS) + s0 + sl) * ND + hi * 8;
    short8 qf[4], q2f[4];
    #pragma unroll
    for (int c = 0; c < 4; ++c) {
        qf[c]  = *(const short8*)(qptr  + 16 * c);
        q2f[c] = *(const short8*)(q2ptr + 16 * c);
    }

    const ushort* kfb  = Kf_ + (size_t)bh * 65536 + sl * 16 + hi * 8;
    const ushort* vfb  = Vf_ + (size_t)bh * 65536 + (sl * 2 + hi) * 8;
    const ushort* efb  = PEKf + sl * 16 + hi * 8;
    const ushort* pevw = PEVf + (size_t)(31 - st) * 2048 + (sl * 2 + hi) * 8;
    const int RBASE = NL - 31 - s0;

    // chunk c -> Mpt[cb+sl][*]; packed b32 writes via memcpy (alias-safe)
    auto mpchunk = [&](int c, int cb) {
        f32x16 cm = {};
        #pragma unroll
        for (int c4 = 0; c4 < 4; ++c4) {
            short8 ef = *(const short8*)(efb + (size_t)c4 * 32784 +
                                         (size_t)(RBASE + 32 * c) * 16);
            cm = __builtin_amdgcn_mfma_f32_32x32x16_bf16(q2f[c4], ef, cm, 0, 0, 0);
        }
        #pragma unroll
        for (int w2 = 0; w2 < 8; ++w2) {
            const int q = 2 * w2;
            const int srow = (q & 3) + 8 * (q >> 2) + 4 * hi;   // even
            unsigned pk = (unsigned)f2bf(cm[q]) | ((unsigned)f2bf(cm[q + 1]) << 16);
            __builtin_memcpy(&Mpt[cb + sl][srow], &pk, 4);
        }
    };

    f32x16 acc0 = {}, acc1 = {};
    float mrow = -1e30f, lrow = 0.f;
    short8 eaA[2][2];

    __builtin_amdgcn_s_setprio(1);
    mpchunk(0, 0);
    mpchunk(1, 32);
    mpchunk(2, 64);
    __builtin_amdgcn_s_setprio(0);
    #pragma unroll
    for (int cc = 0; cc < 2; ++cc)
        #pragma unroll
        for (int a = 0; a < 2; ++a)
            eaA[cc][a] = *(const short8*)(pevw + cc * 1024 + a * 512);

    // ================= pair loop =================
    for (int k = 0; k < Ppairs; ++k) {
        const int t0 = 64 * k;

        short8 kfA[4], kfB[4], vaA[2][2];
        #pragma unroll
        for (int c = 0; c < 4; ++c) {
            kfA[c] = *(const short8*)(kfb + c * 16384 + (size_t)t0 * 16);
            kfB[c] = *(const short8*)(kfb + c * 16384 + (size_t)(t0 + 32) * 16);
        }
        #pragma unroll
        for (int c = 0; c < 2; ++c)
            #pragma unroll
            for (int a = 0; a < 2; ++a)
                vaA[c][a] = *(const short8*)(vfb + (size_t)(2 * k) * 2048 + (a * 2 + c) * 512);

        f32x16 csw0 = {}, csw1 = {};
        __builtin_amdgcn_s_setprio(1);
        #pragma unroll
        for (int c = 0; c < 4; ++c)
            csw0 = __builtin_amdgcn_mfma_f32_32x32x16_bf16(kfA[c], qf[c], csw0, 0, 0, 0);
        #pragma unroll
        for (int c = 0; c < 4; ++c)
            csw1 = __builtin_amdgcn_mfma_f32_32x32x16_bf16(kfB[c], qf[c], csw1, 0, 0, 0);
        __builtin_amdgcn_s_setprio(0);

        float sc[32];
        #pragma unroll
        for (int q = 0; q < 16; ++q) {
            const int trow = (q & 3) + 8 * (q >> 2) + 4 * hi;
            const int u = trow + 31 - sl;
            sc[q]      = (csw0[q] + bf2f(Mpt[u][sl]))      * 0.125f;
            sc[16 + q] = (csw1[q] + bf2f(Mpt[u + 32][sl])) * 0.125f;
        }

        float tm16[16], tm8[8], tm4[4];
        #pragma unroll
        for (int q = 0; q < 16; ++q) tm16[q] = fmaxf(sc[q], sc[q + 16]);
        #pragma unroll
        for (int q = 0; q < 8; ++q) tm8[q] = fmaxf(tm16[q], tm16[q + 8]);
        #pragma unroll
        for (int q = 0; q < 4; ++q) tm4[q] = fmaxf(tm8[q], tm8[q + 4]);
        float tmax = fmaxf(fmaxf(tm4[0], tm4[1]), fmaxf(tm4[2], tm4[3]));
        tmax = fmaxf(tmax, __shfl_xor(tmax, 32));
        if (!__all(tmax <= mrow + 8.f)) {
            const float mnew = fmaxf(mrow, tmax);
            const float r = __expf(mrow - mnew);
            lrow *= r;
            acc0 *= r; acc1 *= r;
            mrow = mnew;
        }
        float ps[32];
        #pragma unroll
        for (int q = 0; q < 32; ++q) ps[q] = __expf(sc[q] - mrow);
        float ls16[16], ls8[8], ls4[4];
        #pragma unroll
        for (int q = 0; q < 16; ++q) ls16[q] = ps[q] + ps[q + 16];
        #pragma unroll
        for (int q = 0; q < 8; ++q) ls8[q] = ls16[q] + ls16[q + 8];
        #pragma unroll
        for (int q = 0; q < 4; ++q) ls4[q] = ls8[q] + ls8[q + 4];
        float lsum = (ls4[0] + ls4[1]) + (ls4[2] + ls4[3]);
        lsum += __shfl_xor(lsum, 32);
        lrow += lsum;

        #pragma unroll
        for (int q = 0; q < 16; ++q) {
            const int trow = (q & 3) + 8 * (q >> 2) + 4 * hi;
            Pb2[sl][trow + 31 - sl] = f2bf(ps[q]);
            Pb2[sl][trow + 63 - sl] = f2bf(ps[16 + q]);
        }

        // window k+1 chunks overwrite the single buffer AFTER this window's
        // gather reads (memcpy writes alias-order vs the ushort reads)
        __builtin_amdgcn_s_setprio(1);
        mpchunk(2 * k + 2, 0);
        mpchunk(2 * k + 3, 32);
        mpchunk(2 * k + 4, 64);
        __builtin_amdgcn_s_setprio(0);

        __builtin_amdgcn_s_setprio(1);
        #pragma unroll
        for (int c = 0; c < 2; ++c) {
            float shc[8];
            #pragma unroll
            for (int j = 0; j < 8; ++j) shc[j] = __shfl_xor(ps[8 * c + j], 32);
            short8 bfrag;
            #pragma unroll
            for (int j = 0; j < 8; ++j) {
                float pv;
                if (j < 4) pv = hi ? shc[4 + j]    : ps[8 * c + j];
                else       pv = hi ? ps[8 * c + j] : shc[j - 4];
                bfrag[j] = (short)f2bf(pv);
            }
            acc0 = __builtin_amdgcn_mfma_f32_32x32x16_bf16(vaA[c][0], bfrag, acc0, 0, 0, 0);
            acc1 = __builtin_amdgcn_mfma_f32_32x32x16_bf16(vaA[c][1], bfrag, acc1, 0, 0, 0);
        }
        // eaB loaded here (deferred): used 2 MFMA-blocks below, L2-hot table
        short8 eaB[2][2];
        #pragma unroll
        for (int cc = 0; cc < 2; ++cc)
            #pragma unroll
            for (int a = 0; a < 2; ++a)
                eaB[cc][a] = *(const short8*)(pevw + (size_t)(2 * k + 1) * 2048 + cc * 1024 + a * 512);
        short8 vaB[2][2];
        #pragma unroll
        for (int c = 0; c < 2; ++c)
            #pragma unroll
            for (int a = 0; a < 2; ++a)
                vaB[c][a] = *(const short8*)(vfb + (size_t)(2 * k + 1) * 2048 + (a * 2 + c) * 512);
        #pragma unroll
        for (int c = 0; c < 2; ++c) {
            float shc[8];
            #pragma unroll
            for (int j = 0; j < 8; ++j) shc[j] = __shfl_xor(ps[16 + 8 * c + j], 32);
            short8 bfrag;
            #pragma unroll
            for (int j = 0; j < 8; ++j) {
                float pv;
                if (j < 4) pv = hi ? shc[4 + j]         : ps[16 + 8 * c + j];
                else       pv = hi ? ps[16 + 8 * c + j] : shc[j - 4];
                bfrag[j] = (short)f2bf(pv);
            }
            acc0 = __builtin_amdgcn_mfma_f32_32x32x16_bf16(vaB[c][0], bfrag, acc0, 0, 0, 0);
            acc1 = __builtin_amdgcn_mfma_f32_32x32x16_bf16(vaB[c][1], bfrag, acc1, 0, 0, 0);
        }

        // eaC loaded here (deferred): used 4 MFMA-blocks below
        short8 eaC[2][2];
        #pragma unroll
        for (int cc = 0; cc < 2; ++cc)
            #pragma unroll
            for (int a = 0; a < 2; ++a)
                eaC[cc][a] = *(const short8*)(pevw + (size_t)(2 * k + 2) * 2048 + cc * 1024 + a * 512);

        {
            short8 pk0 = *(const short8*)&Pb2[sl][0 + 8 * hi];
            acc0 = __builtin_amdgcn_mfma_f32_32x32x16_bf16(eaA[0][0], pk0, acc0, 0, 0, 0);
            acc1 = __builtin_amdgcn_mfma_f32_32x32x16_bf16(eaA[0][1], pk0, acc1, 0, 0, 0);
            short8 pk1 = *(const short8*)&Pb2[sl][16 + 8 * hi];
            acc0 = __builtin_amdgcn_mfma_f32_32x32x16_bf16(eaA[1][0], pk1, acc0, 0, 0, 0);
            acc1 = __builtin_amdgcn_mfma_f32_32x32x16_bf16(eaA[1][1], pk1, acc1, 0, 0, 0);
            short8 pk2 = *(const short8*)&Pb2[sl][32 + 8 * hi];
            acc0 = __builtin_amdgcn_mfma_f32_32x32x16_bf16(eaB[0][0], pk2, acc0, 0, 0, 0);
            acc1 = __builtin_amdgcn_mfma_f32_32x32x16_bf16(eaB[0][1], pk2, acc1, 0, 0, 0);
            short8 pk3 = *(const short8*)&Pb2[sl][48 + 8 * hi];
            acc0 = __builtin_amdgcn_mfma_f32_32x32x16_bf16(eaB[1][0], pk3, acc0, 0, 0, 0);
            acc1 = __builtin_amdgcn_mfma_f32_32x32x16_bf16(eaB[1][1], pk3, acc1, 0, 0, 0);
            short8 pk4 = *(const short8*)&Pb2[sl][64 + 8 * hi];
            acc0 = __builtin_amdgcn_mfma_f32_32x32x16_bf16(eaC[0][0], pk4, acc0, 0, 0, 0);
            acc1 = __builtin_amdgcn_mfma_f32_32x32x16_bf16(eaC[0][1], pk4, acc1, 0, 0, 0);
            short8 pk5 = *(const short8*)&Pb2[sl][80 + 8 * hi];
            acc0 = __builtin_amdgcn_mfma_f32_32x32x16_bf16(eaC[1][0], pk5, acc0, 0, 0, 0);
            acc1 = __builtin_amdgcn_mfma_f32_32x32x16_bf16(eaC[1][1], pk5, acc1, 0, 0, 0);
        }
        __builtin_amdgcn_s_setprio(0);

        #pragma unroll
        for (int cc = 0; cc < 2; ++cc)
            #pragma unroll
            for (int a = 0; a < 2; ++a)
                eaA[cc][a] = eaC[cc][a];
    }

    // ================= trailing (1-2 tiles incl. diagonal) =================
    for (int i = i0; i <= st; ++i) {
        const int cb = (i - i0) * 32;
        const int t0 = i * 32;

        short8 kf[4], va[2][2];
        #pragma unroll
        for (int c = 0; c < 4; ++c)
            kf[c] = *(const short8*)(kfb + c * 16384 + (size_t)t0 * 16);
        #pragma unroll
        for (int c = 0; c < 2; ++c)
            #pragma unroll
            for (int a = 0; a < 2; ++a)
                va[c][a] = *(const short8*)(vfb + (size_t)i * 2048 + (a * 2 + c) * 512);

        f32x16 csw = {};
        __builtin_amdgcn_s_setprio(1);
        #pragma unroll
        for (int c = 0; c < 4; ++c)
            csw = __builtin_amdgcn_mfma_f32_32x32x16_bf16(kf[c], qf[c], csw, 0, 0, 0);
        __builtin_amdgcn_s_setprio(0);

        float sc[16];
        #pragma unroll
        for (int q = 0; q < 16; ++q) {
            const int trow = (q & 3) + 8 * (q >> 2) + 4 * hi;
            const int u = cb + trow + 31 - sl;
            sc[q] = (csw[q] + bf2f(Mpt[u][sl])) * 0.125f;
        }
        if (i == st) {
            #pragma unroll
            for (int q = 0; q < 16; ++q) {
                const int trow = (q & 3) + 8 * (q >> 2) + 4 * hi;
                if (t0 + trow > s0 + sl) sc[q] = -1e30f;
            }
        }
        float tm8[8], tm4[4];
        #pragma unroll
        for (int q = 0; q < 8; ++q) tm8[q] = fmaxf(sc[q], sc[q + 8]);
        #pragma unroll
        for (int q = 0; q < 4; ++q) tm4[q] = fmaxf(tm8[q], tm8[q + 4]);
        float tmax = fmaxf(fmaxf(tm4[0], tm4[1]), fmaxf(tm4[2], tm4[3]));
        tmax = fmaxf(tmax, __shfl_xor(tmax, 32));
        if (!__all(tmax <= mrow + 8.f)) {
            const float mnew = fmaxf(mrow, tmax);
            const float r = __expf(mrow - mnew);
            lrow *= r;
            acc0 *= r; acc1 *= r;
            mrow = mnew;
        }
        float ps[16];
        #pragma unroll
        for (int q = 0; q < 16; ++q) ps[q] = __expf(sc[q] - mrow);
        float ls8[8], ls4[4];
        #pragma unroll
        for (int q = 0; q < 8; ++q) ls8[q] = ps[q] + ps[q + 8];
        #pragma unroll
        for (int q = 0; q < 4; ++q) ls4[q] = ls8[q] + ls8[q + 4];
        float lsum = (ls4[0] + ls4[1]) + (ls4[2] + ls4[3]);
        lsum += __shfl_xor(lsum, 32);
        lrow += lsum;

        #pragma unroll
        for (int q = 0; q < 16; ++q) {
            const int trow = (q & 3) + 8 * (q >> 2) + 4 * hi;
            Pb2[sl][trow + 31 - sl] = f2bf(ps[q]);
        }
        if (i == i0 && Ppairs > 0) {
            #pragma unroll
            for (int jj = 0; jj < 16; ++jj)
                Pb2[sl][63 - sl + 16 * hi + jj] = 0;
        }

        __builtin_amdgcn_s_setprio(1);
        #pragma unroll
        for (int c = 0; c < 2; ++c) {
            float shc[8];
            #pragma unroll
            for (int j = 0; j < 8; ++j) shc[j] = __shfl_xor(ps[8 * c + j], 32);
            short8 bfrag;
            #pragma unroll
            for (int j = 0; j < 8; ++j) {
                float pv;
                if (j < 4) pv = hi ? shc[4 + j]    : ps[8 * c + j];
                else       pv = hi ? ps[8 * c + j] : shc[j - 4];
                bfrag[j] = (short)f2bf(pv);
            }
            acc0 = __builtin_amdgcn_mfma_f32_32x32x16_bf16(va[c][0], bfrag, acc0, 0, 0, 0);
            acc1 = __builtin_amdgcn_mfma_f32_32x32x16_bf16(va[c][1], bfrag, acc1, 0, 0, 0);
        }

        short8 eaF[2][2];
        #pragma unroll
        for (int cc = 0; cc < 2; ++cc)
            #pragma unroll
            for (int a = 0; a < 2; ++a)
                eaF[cc][a] = *(const short8*)(pevw + (size_t)(i + 1) * 2048 + cc * 1024 + a * 512);
        {
            short8 pk0 = *(const short8*)&Pb2[sl][0 + 8 * hi];
            acc0 = __builtin_amdgcn_mfma_f32_32x32x16_bf16(eaA[0][0], pk0, acc0, 0, 0, 0);
            acc1 = __builtin_amdgcn_mfma_f32_32x32x16_bf16(eaA[0][1], pk0, acc1, 0, 0, 0);
            short8 pk1 = *(const short8*)&Pb2[sl][16 + 8 * hi];
            acc0 = __builtin_amdgcn_mfma_f32_32x32x16_bf16(eaA[1][0], pk1, acc0, 0, 0, 0);
            acc1 = __builtin_amdgcn_mfma_f32_32x32x16_bf16(eaA[1][1], pk1, acc1, 0, 0, 0);
            short8 pk2 = *(const short8*)&Pb2[sl][32 + 8 * hi];
            acc0 = __builtin_amdgcn_mfma_f32_32x32x16_bf16(eaF[0][0], pk2, acc0, 0, 0, 0);
            acc1 = __builtin_amdgcn_mfma_f32_32x32x16_bf16(eaF[0][1], pk2, acc1, 0, 0, 0);
            short8 pk3 = *(const short8*)&Pb2[sl][48 + 8 * hi];
            acc0 = __builtin_amdgcn_mfma_f32_32x32x16_bf16(eaF[1][0], pk3, acc0, 0, 0, 0);
            acc1 = __builtin_amdgcn_mfma_f32_32x32x16_bf16(eaF[1][1], pk3, acc1, 0, 0, 0);
        }
        __builtin_amdgcn_s_setprio(0);

        #pragma unroll
        for (int cc = 0; cc < 2; ++cc)
            #pragma unroll
            for (int a = 0; a < 2; ++a)
                eaA[cc][a] = eaF[cc][a];
    }

    // ---- epilogue: bf16 packed stores ----
    const float inv = 1.0f / lrow;
    ushort* orow = AO + ((size_t)b * NS + s0 + sl) * NE + h * ND;
    #pragma unroll
    for (int g = 0; g < 4; ++g) {
        ushort4 o0 = make_ushort4(f2bf(acc0[4*g+0]*inv), f2bf(acc0[4*g+1]*inv),
                                  f2bf(acc0[4*g+2]*inv), f2bf(acc0[4*g+3]*inv));
        ushort4 o1 = make_ushort4(f2bf(acc1[4*g+0]*inv), f2bf(acc1[4*g+1]*inv),
                                  f2bf(acc1[4*g+2]*inv), f2bf(acc1[4*g+3]*inv));
        *(ushort4*)&orow[8 * g + 4 * hi]      = o0;
        *(ushort4*)&orow[8 * g + 4 * hi + 32] = o1;
    }
}

extern "C" void kernel_launch(void* const* d_in, const int* in_sizes, int n_in,
                              void* d_out, int out_size, void* d_ws, size_t ws_size,
                              hipStream_t stream) {
    const float* x   = (const float*)d_in[0];
    const float* Wq  = (const float*)d_in[2];
    const float* Wk  = (const float*)d_in[3];
    const float* Wv  = (const float*)d_in[4];
    const float* Wo  = (const float*)d_in[5];
    const float* pek = (const float*)d_in[6];
    const float* pev = (const float*)d_in[7];

    ushort* ws16 = (ushort*)d_ws;
    size_t off = 0;
    ushort* xb    = ws16 + off; off += (size_t)8388608;   // [8192,1024] bf16
    ushort* Wqb   = ws16 + off; off += (size_t)1048576;   // Wq|Wk|Wv|Wo contiguous
    ushort* Wkb   = ws16 + off; off += (size_t)1048576;
    ushort* Wvb   = ws16 + off; off += (size_t)1048576;
    ushort* Wob   = ws16 + off; off += (size_t)1048576;
    ushort* Qb    = ws16 + off; off += (size_t)8388608;   // Q row-major | K fm | V fm contiguous
    ushort* Kfm   = ws16 + off; off += (size_t)8388608;
    ushort* Vfm   = ws16 + off; off += (size_t)8388608;
    ushort* PEKf  = ws16 + off; off += (size_t)131136;
    ushort* PEVf  = ws16 + off; off += (size_t)67584;
    ushort* aob   = ws16 + off; off += (size_t)8388608;   // [B,S,E] bf16
    float*  out   = (float*)d_out;
    (void)Wkb; (void)Wvb; (void)Kfm; (void)Vfm;

    dim3 blk(256);
    // merged casts: x (8192 blocks) + W4 (4096) + pe (777)
    cast_all<<<dim3(12288 + (198720 + 255) / 256), blk, 0, stream>>>(
        x, Wq, Wk, Wv, Wo, pek, pev, xb, Wqb, PEKf, PEVf);

    // merged Q/K/V projection: N = 3072 (Wq|Wk|Wv), epilogue by segment
    gemm_mfma<5><<<dim3(64, 24), blk, 0, stream>>>(xb, Wqb, nullptr, Qb);

    attn_mfma<<<dim3(4096), dim3(64), 0, stream>>>(Qb, Qb + 8388608, Qb + 16777216,
                                                   PEKf, PEVf, aob);

    gemm_mfma<1><<<dim3(64, 8), blk, 0, stream>>>(aob, Wob, out, nullptr);
}